// Round 2
// baseline (835.084 us; speedup 1.0000x reference)
//
#include <hip/hip_runtime.h>
#include <stdint.h>

// instant-ngp multilevel hash-grid encoding, MI355X.
// One thread per point; 16 levels fully unrolled with compile-time res.
// Levels 0-7 dense (res^3 <= 2^19), levels 8-15 hashed into 2^19-entry tables.
// Output (B,16,2) fp32 written as 8x 16B nontemporal stores (write-once
// stream; keep L2 for the gather tables).

typedef float nfloat4 __attribute__((ext_vector_type(4)));  // native vec for nontemporal builtin

struct EmbPtrs { const float2* p[16]; };

__global__ __launch_bounds__(256) void hashenc_kernel(
    const float* __restrict__ x, EmbPtrs embs, nfloat4* __restrict__ out, int n)
{
    constexpr int RES[16] = {16,20,25,32,40,50,64,80,101,128,161,203,256,322,406,512};
    constexpr uint32_t P1 = 2654435761u, P2 = 805459861u;
    constexpr uint32_t HMASK = (1u << 19) - 1u;   // n_enc = 2^19, pow2 -> AND

    const int b = blockIdx.x * 256 + threadIdx.x;
    if (b >= n) return;

    const float px = x[3*b+0];
    const float py = x[3*b+1];
    const float pz = x[3*b+2];

    float2 f[16];

#pragma unroll
    for (int l = 0; l < 16; ++l) {
        const int res = RES[l];
        const float rh = (float)res * 0.5f;
        // match reference op order: (x+1)*(res*0.5) - 0.5 in fp32
        const float xp = (px + 1.0f) * rh - 0.5f;
        const float yp = (py + 1.0f) * rh - 0.5f;
        const float zp = (pz + 1.0f) * rh - 0.5f;
        const float fx = floorf(xp), fy = floorf(yp), fz = floorf(zp);
        const int ix = (int)fx, iy = (int)fy, iz = (int)fz;
        const float tx = xp - fx, ty = yp - fy, tz = zp - fz;

        const float wx[2] = {1.0f - tx, tx};
        const float wy[2] = {1.0f - ty, ty};
        const float wz[2] = {1.0f - tz, tz};
        // x in [-1,1] -> ix in [-1, res-1]; full masks anyway (cheap, safe)
        const bool vx[2] = {(ix   >= 0) && (ix   < res), (ix+1 >= 0) && (ix+1 < res)};
        const bool vy[2] = {(iy   >= 0) && (iy   < res), (iy+1 >= 0) && (iy+1 < res)};
        const bool vz[2] = {(iz   >= 0) && (iz   < res), (iz+1 >= 0) && (iz+1 < res)};

        const float2* __restrict__ tab = embs.p[l];
        float ax = 0.0f, ay = 0.0f;

        if (l < 8) {
            // dense: id = c0 + c1*res + c2*res^2 (< res^3 = n_enc when valid)
            const int r2 = res * res;
            const int base = ix + iy * res + iz * r2;
#pragma unroll
            for (int k = 0; k < 2; ++k)
#pragma unroll
            for (int j = 0; j < 2; ++j)
#pragma unroll
            for (int i = 0; i < 2; ++i) {
                const bool v = vx[i] && vy[j] && vz[k];
                const uint32_t idx = v ? (uint32_t)(base + i + j*res + k*r2) : 0u;
                const float w = v ? (wx[i]*wy[j]*wz[k]) : 0.0f;
                const float2 e = tab[idx];
                ax = fmaf(e.x, w, ax);
                ay = fmaf(e.y, w, ay);
            }
        } else {
            // hash: (c0*1) ^ (c1*P1) ^ (c2*P2), mod 2^19
            const uint32_t hx0 = (uint32_t)ix;
            const uint32_t hy0 = (uint32_t)iy * P1;
            const uint32_t hz0 = (uint32_t)iz * P2;
            const uint32_t hx[2] = {hx0, hx0 + 1u};
            const uint32_t hy[2] = {hy0, hy0 + P1};
            const uint32_t hz[2] = {hz0, hz0 + P2};
#pragma unroll
            for (int k = 0; k < 2; ++k)
#pragma unroll
            for (int j = 0; j < 2; ++j)
#pragma unroll
            for (int i = 0; i < 2; ++i) {
                const bool v = vx[i] && vy[j] && vz[k];
                uint32_t idx = (hx[i] ^ hy[j] ^ hz[k]) & HMASK;
                idx = v ? idx : 0u;
                const float w = v ? (wx[i]*wy[j]*wz[k]) : 0.0f;
                const float2 e = tab[idx];
                ax = fmaf(e.x, w, ax);
                ay = fmaf(e.y, w, ay);
            }
        }
        f[l] = make_float2(ax, ay);
    }

    // (B,16,2) fp32 -> 128B contiguous per point; nontemporal (never re-read)
    nfloat4* o = out + (size_t)b * 8;
#pragma unroll
    for (int i = 0; i < 8; ++i) {
        nfloat4 v4;
        v4.x = f[2*i].x;  v4.y = f[2*i].y;
        v4.z = f[2*i+1].x; v4.w = f[2*i+1].y;
        __builtin_nontemporal_store(v4, o + i);
    }
}

extern "C" void kernel_launch(void* const* d_in, const int* in_sizes, int n_in,
                              void* d_out, int out_size, void* d_ws, size_t ws_size,
                              hipStream_t stream) {
    const float* x = (const float*)d_in[0];
    EmbPtrs embs;
    for (int l = 0; l < 16; ++l) embs.p[l] = (const float2*)d_in[1 + l];
    const int n = in_sizes[0] / 3;        // (B,3) fp32
    const int grid = (n + 255) / 256;
    hashenc_kernel<<<grid, 256, 0, stream>>>(x, embs, (nfloat4*)d_out, n);
}